// Round 9
// baseline (1216.583 us; speedup 1.0000x reference)
//
#include <hip/hip_runtime.h>
#include <hip/hip_bf16.h>

#define NN 50000      // nodes
#define NE 100000     // edges
#define NG 2500       // graphs
#define WW 128        // edge-mlp width
#define EPAD 100096   // 782 blocks * 128 edges
#define KCH 264       // K chunks of 32: 8448 = 132 h-rows * 64 (128 hid + 1 bias + 3 zero)

typedef _Float16 h8 __attribute__((ext_vector_type(8)));
typedef _Float16 h4 __attribute__((ext_vector_type(4)));
typedef float    f4 __attribute__((ext_vector_type(4)));

__device__ __forceinline__ float sigf(float x) { return 1.0f / (1.0f + __expf(-x)); }

// zero n4 float4's
__global__ void k_zero4(float4* __restrict__ p, int n4) {
    int i = blockIdx.x * 256 + threadIdx.x;
    if (i < n4) p[i] = make_float4(0.f, 0.f, 0.f, 0.f);
}

// dst[c*rows + r] = src[r*cols + c]
__global__ void k_transpose(float* dst, const float* src, int rows, int cols) {
    int idx = blockIdx.x * 256 + threadIdx.x;
    if (idx >= rows * cols) return;
    int r = idx / cols, c = idx % cols;
    dst[c * rows + r] = src[idx];
}

// s[n,o] = relu([x|z] @ lin0_w + b)
__global__ void k_lin0(const float* __restrict__ x, const float* __restrict__ z,
                       const float* __restrict__ w, const float* __restrict__ b,
                       float* __restrict__ s) {
    int idx = blockIdx.x * 256 + threadIdx.x;  // NN*64 exact
    int n = idx >> 6, o = idx & 63;
    float acc = b[o];
#pragma unroll
    for (int i = 0; i < 15; i++) acc += x[n * 15 + i] * w[i * 64 + o];
    acc += z[n] * w[15 * 64 + o];
    s[idx] = fmaxf(acc, 0.0f);
}

__global__ void k_deg(const int* __restrict__ dstI, float* __restrict__ deg) {
    int e = blockIdx.x * 256 + threadIdx.x;
    if (e < NE) atomicAdd(&deg[dstI[e]], 1.0f);
}

// s -> f16 copy (prologue only; steady-state s16 written by k_combine2)
__global__ void k_s16(const float* __restrict__ s, _Float16* __restrict__ s16) {
    int i = blockIdx.x * 256 + threadIdx.x;  // NN*16 exact
    float4 v = ((const float4*)s)[i];
    h4 o = { (_Float16)v.x, (_Float16)v.y, (_Float16)v.z, (_Float16)v.w };
    *((h4*)s16 + i) = o;
}

// gstart[g] = first node n with batch[n] >= g (batch sorted); gstart[NG] = NN
__global__ void k_gstart(const int* __restrict__ batch, int* __restrict__ gstart) {
    int n = blockIdx.x * 256 + threadIdx.x;
    if (n > NN) return;
    int b1 = (n < NN) ? batch[n] : NG;
    int b0 = (n == 0) ? -1 : batch[n - 1];
    for (int g = b0 + 1; g <= b1; g++) gstart[g] = n;
}

// edge MLP layer 1 -> f16, layout hidT2[sc][e][4] (4 h-rows per sc interleaved per edge)
__global__ void k_emlp_t(const float* __restrict__ ea, const float* __restrict__ w1,
                         const float* __restrict__ b1, _Float16* __restrict__ hidT2) {
    __shared__ _Float16 hl[132][64];
    int t = threadIdx.x;
    int e0 = blockIdx.x * 64;
    int e_l = t & 63, w = t >> 6;
    int e = e0 + e_l;
    float a0 = 0, a1 = 0, a2 = 0, a3 = 0, a4 = 0;
    if (e < NE) {
        a0 = ea[e * 5 + 0]; a1 = ea[e * 5 + 1]; a2 = ea[e * 5 + 2];
        a3 = ea[e * 5 + 3]; a4 = ea[e * 5 + 4];
    }
    for (int h = w * 32; h < w * 32 + 32; h++) {
        float acc = b1[h];
        acc += a0 * w1[0 * 128 + h] + a1 * w1[1 * 128 + h] + a2 * w1[2 * 128 + h]
             + a3 * w1[3 * 128 + h] + a4 * w1[4 * 128 + h];
        hl[h][e_l] = (_Float16)fmaxf(acc, 0.0f);
    }
    if (t < 64) hl[128][t] = (_Float16)1.0f;
    else if (t < 128) hl[129][t - 64] = (_Float16)0.0f;
    else if (t < 192) hl[130][t - 128] = (_Float16)0.0f;
    else hl[131][t - 192] = (_Float16)0.0f;
    __syncthreads();
    for (int idx = t; idx < 33 * 64; idx += 256) {
        int j = idx >> 6, el = idx & 63;
        h4 v = { hl[j * 4 + 0][el], hl[j * 4 + 1][el],
                 hl[j * 4 + 2][el], hl[j * 4 + 3][el] };
        *(h4*)(hidT2 + ((size_t)j * EPAD + e0 + el) * 4) = v;
    }
}

// Pre-arrange B = [w2 ; b2 ; 0] (shape [8448,64]) into MFMA-fragment order
__global__ void k_prep_B(const float* __restrict__ w2, const float* __restrict__ b2,
                         _Float16* __restrict__ Bp) {
    int g = blockIdx.x * 256 + threadIdx.x;   // KCH*4*64 = 67584 exact
    int l = g & 63, tt = (g >> 6) & 3, c = g >> 8;
    int n = tt * 16 + (l & 15);
    int kb = c * 32 + (l >> 4) * 8;
    h8 v;
#pragma unroll
    for (int j = 0; j < 8; j++) {
        int k = kb + j;
        float f = 0.0f;
        if (k < 8192) f = w2[(size_t)k * 64 + n];
        else if (k < 8256) f = b2[(k - 8192) * 64 + n];
        v[j] = (_Float16)f;
    }
    *((h8*)Bp + g) = v;
}

// Pre-arrange combine weights into MFMA B-fragment layout (f16)
__global__ void k_prep_W(const float* __restrict__ conv_root,
                         const float* __restrict__ gru_wi,
                         const float* __restrict__ gru_wh,
                         _Float16* __restrict__ Bw) {
    int g = blockIdx.x * 256 + threadIdx.x;   // 56*64 = 3584
    if (g >= 56 * 64) return;
    int l = g & 63, unit = g >> 6;
    int kb = ((unit & 1) * 32) + (l >> 4) * 8;
    h8 v;
    if (unit < 8) {
        int nt = unit >> 1;
        int n = nt * 16 + (l & 15);
#pragma unroll
        for (int j = 0; j < 8; j++) v[j] = (_Float16)conv_root[(kb + j) * 64 + n];
    } else if (unit < 32) {
        int nt = (unit - 8) >> 1;
        int o = nt * 16 + (l & 15);
#pragma unroll
        for (int j = 0; j < 8; j++) v[j] = (_Float16)gru_wi[o * 64 + kb + j];
    } else {
        int nt = (unit - 32) >> 1;
        int o = nt * 16 + (l & 15);
#pragma unroll
        for (int j = 0; j < 8; j++) v[j] = (_Float16)gru_wh[o * 64 + kb + j];
    }
    *((h8*)Bw + g) = v;
}

// Fused NNConv message v5: no LDS/barriers + K-split x2 for occupancy.
// blockIdx.y selects K-half (sc 0..16 / 17..32); both halves atomicAdd into aggr.
// 2 waves/block, 64 edges/wave, 128 edges/block, grid (782, 2) = 3128 waves.
__global__ __launch_bounds__(128) void k_fused(
        const _Float16* __restrict__ s16, const _Float16* __restrict__ hidT2,
        const _Float16* __restrict__ Bp, const int* __restrict__ srcI,
        const int* __restrict__ dstI, float* __restrict__ aggr) {
    int t = threadIdx.x, w = t >> 6, lane = t & 63;
    int m = lane & 15, q = lane >> 4;
    int e_blk = blockIdx.x * 128;
    int ew0 = e_blk + w * 64;             // wave's 64 edges
    int sc0 = blockIdx.y ? 17 : 0;
    int sc1 = blockIdx.y ? 33 : 17;

    // s A-fragments: [mt][k-half], reused across entire K loop
    h8 sA[4][2];
#pragma unroll
    for (int mt = 0; mt < 4; mt++) {
        int e = ew0 + mt * 16 + m;
        int src = (e < NE) ? srcI[e] : 0;
        const _Float16* sp = s16 + (size_t)src * 64;
        sA[mt][0] = *(const h8*)(sp + q * 8);
        sA[mt][1] = *(const h8*)(sp + 32 + q * 8);
    }
    f4 acc[4][4];
#pragma unroll
    for (int mt = 0; mt < 4; mt++)
#pragma unroll
        for (int nt = 0; nt < 4; nt++) acc[mt][nt] = (f4){0.f, 0.f, 0.f, 0.f};

    const h8* Bg = (const h8*)Bp;
    for (int sc = sc0; sc < sc1; sc++) {
        // hid for this sc's 4 h-rows, per-edge h4 (coalesced dwordx2)
        h4 hf[4];
#pragma unroll
        for (int mt = 0; mt < 4; mt++) {
            int e = ew0 + mt * 16 + m;
            hf[mt] = *(const h4*)(hidT2 + ((size_t)sc * EPAD + e) * 4);
        }
#pragma unroll
        for (int cc = 0; cc < 8; cc++) {
            const h8* bb = Bg + (size_t)((sc * 8 + cc) * 4) * 64 + lane;
            h8 b0 = bb[0];
            h8 b1 = bb[64];
            h8 b2 = bb[128];
            h8 b3 = bb[192];
            int hi = cc >> 1, kh = cc & 1;
#pragma unroll
            for (int mt = 0; mt < 4; mt++) {
                h8 a = sA[mt][kh] * hf[mt][hi];
                acc[mt][0] = __builtin_amdgcn_mfma_f32_16x16x32_f16(a, b0, acc[mt][0], 0, 0, 0);
                acc[mt][1] = __builtin_amdgcn_mfma_f32_16x16x32_f16(a, b1, acc[mt][1], 0, 0, 0);
                acc[mt][2] = __builtin_amdgcn_mfma_f32_16x16x32_f16(a, b2, acc[mt][2], 0, 0, 0);
                acc[mt][3] = __builtin_amdgcn_mfma_f32_16x16x32_f16(a, b3, acc[mt][3], 0, 0, 0);
            }
        }
    }
    // epilogue: C/D layout col=lane&15, row=q*4+reg
#pragma unroll
    for (int mt = 0; mt < 4; mt++) {
        int eb = ew0 + mt * 16 + q * 4;
#pragma unroll
        for (int r = 0; r < 4; r++) {
            int e = eb + r;
            if (e < NE) {
                int d = dstI[e];
                float* ap = aggr + (size_t)d * 64 + m;
                atomicAdd(ap + 0,  acc[mt][0][r]);
                atomicAdd(ap + 16, acc[mt][1][r]);
                atomicAdd(ap + 32, acc[mt][2][r]);
                atomicAdd(ap + 48, acc[mt][3][r]);
            }
        }
    }
}

// MFMA NNConv-root + GRU combine. Block=256 (4 waves), 64 nodes/block.
// Re-zeros aggr after consuming it — ONLY the owning in-range thread touches
// aggr (clamped out-of-range lanes must not write: they'd race with the real
// owner of node NN-1 in another wave of the same block).
__global__ __launch_bounds__(256) void k_combine2(
        float* __restrict__ s, _Float16* __restrict__ s16,
        float* __restrict__ aggr, const float* __restrict__ deg,
        const _Float16* __restrict__ Bw, const float* __restrict__ cb,
        const float* __restrict__ bi, const float* __restrict__ bh) {
    __shared__ _Float16 ml[4][16][72];
    int t = threadIdx.x, w = t >> 6, lane = t & 63;
    int m = lane & 15, q = lane >> 4;
    int nb = blockIdx.x * 64 + w * 16;

    h8 sa0, sa1;
    {
        int node = nb + m; if (node >= NN) node = NN - 1;   // read-only clamp: safe
        const _Float16* sp = s16 + (size_t)node * 64;
        sa0 = *(const h8*)(sp + q * 8);
        sa1 = *(const h8*)(sp + 32 + q * 8);
    }
    const h8* BW = (const h8*)Bw;

    f4 X[4], GH[12];
#pragma unroll
    for (int nt = 0; nt < 4; nt++) {
        X[nt] = (f4){0.f, 0.f, 0.f, 0.f};
        X[nt] = __builtin_amdgcn_mfma_f32_16x16x32_f16(sa0, BW[(nt * 2 + 0) * 64 + lane], X[nt], 0, 0, 0);
        X[nt] = __builtin_amdgcn_mfma_f32_16x16x32_f16(sa1, BW[(nt * 2 + 1) * 64 + lane], X[nt], 0, 0, 0);
    }
#pragma unroll
    for (int nt = 0; nt < 12; nt++) {
        GH[nt] = (f4){0.f, 0.f, 0.f, 0.f};
        GH[nt] = __builtin_amdgcn_mfma_f32_16x16x32_f16(sa0, BW[(32 + nt * 2 + 0) * 64 + lane], GH[nt], 0, 0, 0);
        GH[nt] = __builtin_amdgcn_mfma_f32_16x16x32_f16(sa1, BW[(32 + nt * 2 + 1) * 64 + lane], GH[nt], 0, 0, 0);
    }
#pragma unroll
    for (int r = 0; r < 4; r++) {
        int node = nb + q * 4 + r;
        bool ok = node < NN;
        int nc = ok ? node : NN - 1;
        float dn = fmaxf(deg[nc], 1.0f);
#pragma unroll
        for (int nt = 0; nt < 4; nt++) {
            int o = nt * 16 + m;
            float av = 0.0f;
            if (ok) {
                av = aggr[(size_t)node * 64 + o];
                aggr[(size_t)node * 64 + o] = 0.0f;   // owner-only self-clear
            }
            float mv = X[nt][r] + av / dn + cb[o];
            ml[w][q * 4 + r][o] = (_Float16)fmaxf(mv, 0.0f);
        }
    }
    __syncthreads();
    h8 ma0 = *(const h8*)&ml[w][m][q * 8];
    h8 ma1 = *(const h8*)&ml[w][m][32 + q * 8];

    f4 GI[12];
#pragma unroll
    for (int nt = 0; nt < 12; nt++) {
        GI[nt] = (f4){0.f, 0.f, 0.f, 0.f};
        GI[nt] = __builtin_amdgcn_mfma_f32_16x16x32_f16(ma0, BW[(8 + nt * 2 + 0) * 64 + lane], GI[nt], 0, 0, 0);
        GI[nt] = __builtin_amdgcn_mfma_f32_16x16x32_f16(ma1, BW[(8 + nt * 2 + 1) * 64 + lane], GI[nt], 0, 0, 0);
    }
#pragma unroll
    for (int og = 0; og < 4; og++) {
        int o = og * 16 + m;
        float bir = bi[o],       bhr = bh[o];
        float biz = bi[64 + o],  bhz = bh[64 + o];
        float bin = bi[128 + o], bhn = bh[128 + o];
#pragma unroll
        for (int r = 0; r < 4; r++) {
            int node = nb + q * 4 + r;
            if (node >= NN) continue;
            float rr = sigf(GI[og][r] + bir + GH[og][r] + bhr);
            float zz = sigf(GI[4 + og][r] + biz + GH[4 + og][r] + bhz);
            float ng = tanhf(GI[8 + og][r] + bin + rr * (GH[8 + og][r] + bhn));
            float hold = s[(size_t)node * 64 + o];
            float hnew = (1.0f - zz) * ng + zz * hold;
            s[(size_t)node * 64 + o] = hnew;
            s16[(size_t)node * 64 + o] = (_Float16)hnew;
        }
    }
}

// Fused Set2Set iteration: LSTM cell + attention pooling, one block(256) per graph.
__global__ void k_s2s(float* __restrict__ q_star, float* __restrict__ hh,
                      float* __restrict__ cc, const float* __restrict__ LiT,
                      const float* __restrict__ LhT, const float* __restrict__ bi,
                      const float* __restrict__ bh, const float* __restrict__ s,
                      const int* __restrict__ gstart, float* __restrict__ e_v) {
    __shared__ float qs[128], hv[64], g[256], qn[64];
    int b = blockIdx.x, t = threadIdx.x;
    if (t < 128) qs[t] = q_star[b * 128 + t];
    else if (t < 192) hv[t - 128] = hh[b * 64 + t - 128];
    __syncthreads();
    float acc = bi[t] + bh[t];
    for (int k = 0; k < 128; k++) acc += qs[k] * LiT[k * 256 + t];
    for (int k = 0; k < 64; k++) acc += hv[k] * LhT[k * 256 + t];
    g[t] = acc;
    __syncthreads();
    if (t < 64) {
        float c_new = sigf(g[64 + t]) * cc[b * 64 + t] + sigf(g[t]) * tanhf(g[128 + t]);
        cc[b * 64 + t] = c_new;
        float hq = sigf(g[192 + t]) * tanhf(c_new);
        hh[b * 64 + t] = hq;
        qn[t] = hq;
        q_star[b * 128 + t] = hq;
    }
    __syncthreads();
    if (t >= 64) return;                 // wave 0 does the pooling
    int o = t;
    int n0 = gstart[b], n1 = gstart[b + 1];
    float q = qn[o];
    float mx = -3.4e38f;
    for (int n = n0; n < n1; n++) {
        float v = s[(size_t)n * 64 + o] * q;
#pragma unroll
        for (int off = 32; off; off >>= 1) v += __shfl_xor(v, off, 64);
        if (o == 0) e_v[n] = v;
        mx = fmaxf(mx, v);
    }
    float asum = 0.0f, rp = 0.0f;
    for (int n = n0; n < n1; n++) {
        float a = __expf(e_v[n] - mx);
        asum += a;
        rp += a * s[(size_t)n * 64 + o];
    }
    q_star[b * 128 + 64 + o] = rp / (asum + 1e-16f);
}

// y[b] = relu(q_star @ lin1 + b1) @ lin2 + b2 ; one wave per graph
__global__ void k_final(const float* __restrict__ q_star, const float* __restrict__ w1,
                        const float* __restrict__ b1, const float* __restrict__ w2,
                        const float* __restrict__ b2, float* __restrict__ y) {
    __shared__ float qs[128];
    int b = blockIdx.x, t = threadIdx.x;  // 64 threads
    qs[t] = q_star[b * 128 + t];
    qs[64 + t] = q_star[b * 128 + 64 + t];
    __syncthreads();
    float acc = b1[t];
    for (int k = 0; k < 128; k++) acc += qs[k] * w1[k * 64 + t];
    float hid = fmaxf(acc, 0.0f) * w2[t];
#pragma unroll
    for (int off = 32; off; off >>= 1) hid += __shfl_down(hid, off, 64);
    if (t == 0) y[b] = hid + b2[0];
}

static inline void zero_f(float* p, size_t nfloats, hipStream_t stream) {
    int n4 = (int)(nfloats / 4);
    k_zero4<<<(n4 + 255) / 256, 256, 0, stream>>>((float4*)p, n4);
}

extern "C" void kernel_launch(void* const* d_in, const int* in_sizes, int n_in,
                              void* d_out, int out_size, void* d_ws, size_t ws_size,
                              hipStream_t stream) {
    const float* x       = (const float*)d_in[0];
    const float* z       = (const float*)d_in[1];
    const float* ea      = (const float*)d_in[2];
    const float* lin0_w  = (const float*)d_in[3];
    const float* lin0_b  = (const float*)d_in[4];
    const float* emlp_w1 = (const float*)d_in[5];
    const float* emlp_b1 = (const float*)d_in[6];
    const float* emlp_w2 = (const float*)d_in[7];
    const float* emlp_b2 = (const float*)d_in[8];
    const float* conv_r  = (const float*)d_in[9];
    const float* conv_b  = (const float*)d_in[10];
    const float* gru_wi  = (const float*)d_in[11];
    const float* gru_wh  = (const float*)d_in[12];
    const float* gru_bi  = (const float*)d_in[13];
    const float* gru_bh  = (const float*)d_in[14];
    const float* lstm_wi = (const float*)d_in[15];
    const float* lstm_wh = (const float*)d_in[16];
    const float* lstm_bi = (const float*)d_in[17];
    const float* lstm_bh = (const float*)d_in[18];
    const float* lin1_w  = (const float*)d_in[19];
    const float* lin1_b  = (const float*)d_in[20];
    const float* lin2_w  = (const float*)d_in[21];
    const float* lin2_b  = (const float*)d_in[22];
    const int* eidx      = (const int*)d_in[23];
    const int* batch     = (const int*)d_in[24];
    const int* srcI = eidx;
    const int* dstI = eidx + NE;
    float* y = (float*)d_out;

    char* w = (char*)d_ws;
    size_t off = 0;
    auto alloc = [&](size_t bytes) -> void* {
        void* p = w + off;
        off += (bytes + 255) & ~(size_t)255;
        return p;
    };
    float* s      = (float*)alloc((size_t)NN * 64 * 4);
    float* aggr   = (float*)alloc((size_t)NN * 64 * 4);
    float* deg    = (float*)alloc((size_t)NN * 4);
    float* e_v    = (float*)alloc((size_t)NN * 4);
    // contiguous zero region: q_star | hh | cc (all 256-multiples)
    float* q_star = (float*)alloc((size_t)NG * 128 * 4);
    float* hh     = (float*)alloc((size_t)NG * 64 * 4);
    float* cc     = (float*)alloc((size_t)NG * 64 * 4);
    float* LiT    = (float*)alloc(256 * 128 * 4);
    float* LhT    = (float*)alloc(256 * 64 * 4);
    int*   gstart = (int*)alloc((size_t)(NG + 1) * 4);
    _Float16* s16 = (_Float16*)alloc((size_t)NN * 64 * 2);
    _Float16* hidT2 = (_Float16*)alloc((size_t)33 * EPAD * 4 * 2);
    _Float16* Bp  = (_Float16*)alloc((size_t)KCH * 4 * 64 * 8 * 2);
    _Float16* Bw  = (_Float16*)alloc((size_t)56 * 64 * 8 * 2);
    (void)ws_size;  // ~64 MB total, well under proven capacity

    // weight prep
    k_transpose<<<(256 * 128 + 255) / 256, 256, 0, stream>>>(LiT, lstm_wi, 256, 128);
    k_transpose<<<(256 * 64 + 255) / 256, 256, 0, stream>>>(LhT, lstm_wh, 256, 64);
    k_prep_W<<<14, 256, 0, stream>>>(conv_r, gru_wi, gru_wh, Bw);

    // node embedding, degree, graph ranges, edge-MLP layer 1 (-> hidT2 f16), B prep
    k_lin0<<<NN * 64 / 256, 256, 0, stream>>>(x, z, lin0_w, lin0_b, s);
    k_s16<<<NN * 16 / 256, 256, 0, stream>>>(s, s16);
    zero_f(deg, NN, stream);
    k_deg<<<(NE + 255) / 256, 256, 0, stream>>>(dstI, deg);
    k_gstart<<<(NN + 256) / 256, 256, 0, stream>>>(batch, gstart);
    k_emlp_t<<<EPAD / 64, 256, 0, stream>>>(ea, emlp_w1, emlp_b1, hidT2);
    k_prep_B<<<KCH * 4 * 64 / 256, 256, 0, stream>>>(emlp_w2, emlp_b2, Bp);

    // 5 message-passing + GRU steps (aggr zeroed once; k_combine2 self-clears it)
    zero_f(aggr, (size_t)NN * 64, stream);
    for (int step = 0; step < 5; step++) {
        k_fused<<<dim3(EPAD / 128, 2), 128, 0, stream>>>(s16, hidT2, Bp, srcI, dstI, aggr);
        k_combine2<<<(NN + 63) / 64, 256, 0, stream>>>(s, s16, aggr, deg, Bw,
                                                       conv_b, gru_bi, gru_bh);
    }

    // Set2Set: 5 fused LSTM+pool iterations
    zero_f(q_star, (size_t)NG * 128 + NG * 64 + NG * 64, stream);
    for (int it = 0; it < 5; it++) {
        k_s2s<<<NG, 256, 0, stream>>>(q_star, hh, cc, LiT, LhT, lstm_bi, lstm_bh,
                                      s, gstart, e_v);
    }
    k_final<<<NG, 64, 0, stream>>>(q_star, lin1_w, lin1_b, lin2_w, lin2_b, y);
}

// Round 10
// 1084.707 us; speedup vs baseline: 1.1216x; 1.1216x over previous
//
#include <hip/hip_runtime.h>
#include <hip/hip_bf16.h>

#define NN 50000      // nodes
#define NE 100000     // edges
#define NG 2500       // graphs
#define WW 128        // edge-mlp width
#define EPAD 100096   // 782 blocks * 128 edges
#define KCH 264       // K chunks of 32: 8448 = 132 h-rows * 64 (128 hid + 1 bias + 3 zero)

typedef _Float16 h8 __attribute__((ext_vector_type(8)));
typedef _Float16 h4 __attribute__((ext_vector_type(4)));
typedef float    f4 __attribute__((ext_vector_type(4)));

__device__ __forceinline__ float sigf(float x) { return 1.0f / (1.0f + __expf(-x)); }

// zero n4 float4's
__global__ void k_zero4(float4* __restrict__ p, int n4) {
    int i = blockIdx.x * 256 + threadIdx.x;
    if (i < n4) p[i] = make_float4(0.f, 0.f, 0.f, 0.f);
}

// dst[c*rows + r] = src[r*cols + c]
__global__ void k_transpose(float* dst, const float* src, int rows, int cols) {
    int idx = blockIdx.x * 256 + threadIdx.x;
    if (idx >= rows * cols) return;
    int r = idx / cols, c = idx % cols;
    dst[c * rows + r] = src[idx];
}

// s[n,o] = relu([x|z] @ lin0_w + b)
__global__ void k_lin0(const float* __restrict__ x, const float* __restrict__ z,
                       const float* __restrict__ w, const float* __restrict__ b,
                       float* __restrict__ s) {
    int idx = blockIdx.x * 256 + threadIdx.x;  // NN*64 exact
    int n = idx >> 6, o = idx & 63;
    float acc = b[o];
#pragma unroll
    for (int i = 0; i < 15; i++) acc += x[n * 15 + i] * w[i * 64 + o];
    acc += z[n] * w[15 * 64 + o];
    s[idx] = fmaxf(acc, 0.0f);
}

__global__ void k_deg(const int* __restrict__ dstI, float* __restrict__ deg) {
    int e = blockIdx.x * 256 + threadIdx.x;
    if (e < NE) atomicAdd(&deg[dstI[e]], 1.0f);
}

// s -> f16 copy (prologue only; steady-state s16 written by k_combine2)
__global__ void k_s16(const float* __restrict__ s, _Float16* __restrict__ s16) {
    int i = blockIdx.x * 256 + threadIdx.x;  // NN*16 exact
    float4 v = ((const float4*)s)[i];
    h4 o = { (_Float16)v.x, (_Float16)v.y, (_Float16)v.z, (_Float16)v.w };
    *((h4*)s16 + i) = o;
}

// gstart[g] = first node n with batch[n] >= g (batch sorted); gstart[NG] = NN
__global__ void k_gstart(const int* __restrict__ batch, int* __restrict__ gstart) {
    int n = blockIdx.x * 256 + threadIdx.x;
    if (n > NN) return;
    int b1 = (n < NN) ? batch[n] : NG;
    int b0 = (n == 0) ? -1 : batch[n - 1];
    for (int g = b0 + 1; g <= b1; g++) gstart[g] = n;
}

// edge MLP layer 1 -> f16, layout hidT2[sc][e][4] (4 h-rows per sc interleaved per edge)
__global__ void k_emlp_t(const float* __restrict__ ea, const float* __restrict__ w1,
                         const float* __restrict__ b1, _Float16* __restrict__ hidT2) {
    __shared__ _Float16 hl[132][64];
    int t = threadIdx.x;
    int e0 = blockIdx.x * 64;
    int e_l = t & 63, w = t >> 6;
    int e = e0 + e_l;
    float a0 = 0, a1 = 0, a2 = 0, a3 = 0, a4 = 0;
    if (e < NE) {
        a0 = ea[e * 5 + 0]; a1 = ea[e * 5 + 1]; a2 = ea[e * 5 + 2];
        a3 = ea[e * 5 + 3]; a4 = ea[e * 5 + 4];
    }
    for (int h = w * 32; h < w * 32 + 32; h++) {
        float acc = b1[h];
        acc += a0 * w1[0 * 128 + h] + a1 * w1[1 * 128 + h] + a2 * w1[2 * 128 + h]
             + a3 * w1[3 * 128 + h] + a4 * w1[4 * 128 + h];
        hl[h][e_l] = (_Float16)fmaxf(acc, 0.0f);
    }
    if (t < 64) hl[128][t] = (_Float16)1.0f;
    else if (t < 128) hl[129][t - 64] = (_Float16)0.0f;
    else if (t < 192) hl[130][t - 128] = (_Float16)0.0f;
    else hl[131][t - 192] = (_Float16)0.0f;
    __syncthreads();
    for (int idx = t; idx < 33 * 64; idx += 256) {
        int j = idx >> 6, el = idx & 63;
        h4 v = { hl[j * 4 + 0][el], hl[j * 4 + 1][el],
                 hl[j * 4 + 2][el], hl[j * 4 + 3][el] };
        *(h4*)(hidT2 + ((size_t)j * EPAD + e0 + el) * 4) = v;
    }
}

// Pre-arrange B = [w2 ; b2 ; 0] (shape [8448,64]) into MFMA-fragment order
__global__ void k_prep_B(const float* __restrict__ w2, const float* __restrict__ b2,
                         _Float16* __restrict__ Bp) {
    int g = blockIdx.x * 256 + threadIdx.x;   // KCH*4*64 = 67584 exact
    int l = g & 63, tt = (g >> 6) & 3, c = g >> 8;
    int n = tt * 16 + (l & 15);
    int kb = c * 32 + (l >> 4) * 8;
    h8 v;
#pragma unroll
    for (int j = 0; j < 8; j++) {
        int k = kb + j;
        float f = 0.0f;
        if (k < 8192) f = w2[(size_t)k * 64 + n];
        else if (k < 8256) f = b2[(k - 8192) * 64 + n];
        v[j] = (_Float16)f;
    }
    *((h8*)Bp + g) = v;
}

// Pre-arrange combine weights into MFMA B-fragment layout (f16)
__global__ void k_prep_W(const float* __restrict__ conv_root,
                         const float* __restrict__ gru_wi,
                         const float* __restrict__ gru_wh,
                         _Float16* __restrict__ Bw) {
    int g = blockIdx.x * 256 + threadIdx.x;   // 56*64 = 3584
    if (g >= 56 * 64) return;
    int l = g & 63, unit = g >> 6;
    int kb = ((unit & 1) * 32) + (l >> 4) * 8;
    h8 v;
    if (unit < 8) {
        int nt = unit >> 1;
        int n = nt * 16 + (l & 15);
#pragma unroll
        for (int j = 0; j < 8; j++) v[j] = (_Float16)conv_root[(kb + j) * 64 + n];
    } else if (unit < 32) {
        int nt = (unit - 8) >> 1;
        int o = nt * 16 + (l & 15);
#pragma unroll
        for (int j = 0; j < 8; j++) v[j] = (_Float16)gru_wi[o * 64 + kb + j];
    } else {
        int nt = (unit - 32) >> 1;
        int o = nt * 16 + (l & 15);
#pragma unroll
        for (int j = 0; j < 8; j++) v[j] = (_Float16)gru_wh[o * 64 + kb + j];
    }
    *((h8*)Bw + g) = v;
}

// Fused NNConv message v6: no LDS, no barriers, REGISTER double-buffered B at
// half-super-chunk granularity. Each 16-fragment load batch issues ~64 MFMA
// (~310 cyc) before its first use -> L2 latency covered per-wave.
// 2 waves/block, 64 edges/wave (4 m-tiles), 128 edges/block, 782 blocks.
__global__ __launch_bounds__(128) void k_fused(
        const _Float16* __restrict__ s16, const _Float16* __restrict__ hidT2,
        const _Float16* __restrict__ Bp, const int* __restrict__ srcI,
        const int* __restrict__ dstI, float* __restrict__ aggr) {
    int t = threadIdx.x, w = t >> 6, lane = t & 63;
    int m = lane & 15, q = lane >> 4;
    int e_blk = blockIdx.x * 128;
    int ew0 = e_blk + w * 64;             // wave's 64 edges

    // s A-fragments: [mt][k-half], reused across entire K loop
    h8 sA[4][2];
#pragma unroll
    for (int mt = 0; mt < 4; mt++) {
        int e = ew0 + mt * 16 + m;
        int src = (e < NE) ? srcI[e] : 0;
        const _Float16* sp = s16 + (size_t)src * 64;
        sA[mt][0] = *(const h8*)(sp + q * 8);
        sA[mt][1] = *(const h8*)(sp + 32 + q * 8);
    }
    f4 acc[4][4];
#pragma unroll
    for (int mt = 0; mt < 4; mt++)
#pragma unroll
        for (int nt = 0; nt < 4; nt++) acc[mt][nt] = (f4){0.f, 0.f, 0.f, 0.f};

    const h8* Bg = (const h8*)Bp + lane;  // unit u at Bg[u*64]
    h8 Ba[16], Bb[16];                    // half-sc buffers: [cc2*4+nt]
    h4 hfc[4], hfn[4];

    // prologue: Ba <- half0(sc=0) (units 0..15); hfc <- hid(sc=0)
#pragma unroll
    for (int i = 0; i < 16; i++) Ba[i] = Bg[(size_t)i * 64];
#pragma unroll
    for (int mt = 0; mt < 4; mt++)
        hfc[mt] = *(const h4*)(hidT2 + ((size_t)(ew0 + mt * 16 + m)) * 4);

    for (int sc = 0; sc < 33; sc++) {
        // issue Bb <- half1(sc): units sc*32+16 .. +31
#pragma unroll
        for (int i = 0; i < 16; i++) Bb[i] = Bg[((size_t)sc * 32 + 16 + i) * 64];
        if (sc < 32) {                    // prefetch hid(sc+1)
#pragma unroll
            for (int mt = 0; mt < 4; mt++)
                hfn[mt] = *(const h4*)(hidT2 + ((size_t)(sc + 1) * EPAD + ew0 + mt * 16 + m) * 4);
        }
        // compute half0 (orig cc 0..3): hi = cc>>1, kh = cc&1
#pragma unroll
        for (int cc = 0; cc < 4; cc++) {
            int hi = cc >> 1, kh = cc & 1;
#pragma unroll
            for (int mt = 0; mt < 4; mt++) {
                h8 a = sA[mt][kh] * hfc[mt][hi];
                acc[mt][0] = __builtin_amdgcn_mfma_f32_16x16x32_f16(a, Ba[cc * 4 + 0], acc[mt][0], 0, 0, 0);
                acc[mt][1] = __builtin_amdgcn_mfma_f32_16x16x32_f16(a, Ba[cc * 4 + 1], acc[mt][1], 0, 0, 0);
                acc[mt][2] = __builtin_amdgcn_mfma_f32_16x16x32_f16(a, Ba[cc * 4 + 2], acc[mt][2], 0, 0, 0);
                acc[mt][3] = __builtin_amdgcn_mfma_f32_16x16x32_f16(a, Ba[cc * 4 + 3], acc[mt][3], 0, 0, 0);
            }
        }
        // issue Ba <- half0(sc+1): units (sc+1)*32 .. +15
        if (sc < 32) {
#pragma unroll
            for (int i = 0; i < 16; i++) Ba[i] = Bg[((size_t)(sc + 1) * 32 + i) * 64];
        }
        // compute half1 (orig cc 4..7): hi = 2 + (cc>>1), kh = cc&1
#pragma unroll
        for (int cc = 0; cc < 4; cc++) {
            int hi = 2 + (cc >> 1), kh = cc & 1;
#pragma unroll
            for (int mt = 0; mt < 4; mt++) {
                h8 a = sA[mt][kh] * hfc[mt][hi];
                acc[mt][0] = __builtin_amdgcn_mfma_f32_16x16x32_f16(a, Bb[cc * 4 + 0], acc[mt][0], 0, 0, 0);
                acc[mt][1] = __builtin_amdgcn_mfma_f32_16x16x32_f16(a, Bb[cc * 4 + 1], acc[mt][1], 0, 0, 0);
                acc[mt][2] = __builtin_amdgcn_mfma_f32_16x16x32_f16(a, Bb[cc * 4 + 2], acc[mt][2], 0, 0, 0);
                acc[mt][3] = __builtin_amdgcn_mfma_f32_16x16x32_f16(a, Bb[cc * 4 + 3], acc[mt][3], 0, 0, 0);
            }
        }
#pragma unroll
        for (int mt = 0; mt < 4; mt++) hfc[mt] = hfn[mt];
    }
    // epilogue: C/D layout col=lane&15, row=q*4+reg
#pragma unroll
    for (int mt = 0; mt < 4; mt++) {
        int eb = ew0 + mt * 16 + q * 4;
#pragma unroll
        for (int r = 0; r < 4; r++) {
            int e = eb + r;
            if (e < NE) {
                int d = dstI[e];
                float* ap = aggr + (size_t)d * 64 + m;
                atomicAdd(ap + 0,  acc[mt][0][r]);
                atomicAdd(ap + 16, acc[mt][1][r]);
                atomicAdd(ap + 32, acc[mt][2][r]);
                atomicAdd(ap + 48, acc[mt][3][r]);
            }
        }
    }
}

// MFMA NNConv-root + GRU combine. Block=256 (4 waves), 64 nodes/block.
// Re-zeros aggr after consuming it — ONLY the owning in-range thread touches aggr.
__global__ __launch_bounds__(256) void k_combine2(
        float* __restrict__ s, _Float16* __restrict__ s16,
        float* __restrict__ aggr, const float* __restrict__ deg,
        const _Float16* __restrict__ Bw, const float* __restrict__ cb,
        const float* __restrict__ bi, const float* __restrict__ bh) {
    __shared__ _Float16 ml[4][16][72];
    int t = threadIdx.x, w = t >> 6, lane = t & 63;
    int m = lane & 15, q = lane >> 4;
    int nb = blockIdx.x * 64 + w * 16;

    h8 sa0, sa1;
    {
        int node = nb + m; if (node >= NN) node = NN - 1;   // read-only clamp: safe
        const _Float16* sp = s16 + (size_t)node * 64;
        sa0 = *(const h8*)(sp + q * 8);
        sa1 = *(const h8*)(sp + 32 + q * 8);
    }
    const h8* BW = (const h8*)Bw;

    f4 X[4], GH[12];
#pragma unroll
    for (int nt = 0; nt < 4; nt++) {
        X[nt] = (f4){0.f, 0.f, 0.f, 0.f};
        X[nt] = __builtin_amdgcn_mfma_f32_16x16x32_f16(sa0, BW[(nt * 2 + 0) * 64 + lane], X[nt], 0, 0, 0);
        X[nt] = __builtin_amdgcn_mfma_f32_16x16x32_f16(sa1, BW[(nt * 2 + 1) * 64 + lane], X[nt], 0, 0, 0);
    }
#pragma unroll
    for (int nt = 0; nt < 12; nt++) {
        GH[nt] = (f4){0.f, 0.f, 0.f, 0.f};
        GH[nt] = __builtin_amdgcn_mfma_f32_16x16x32_f16(sa0, BW[(32 + nt * 2 + 0) * 64 + lane], GH[nt], 0, 0, 0);
        GH[nt] = __builtin_amdgcn_mfma_f32_16x16x32_f16(sa1, BW[(32 + nt * 2 + 1) * 64 + lane], GH[nt], 0, 0, 0);
    }
#pragma unroll
    for (int r = 0; r < 4; r++) {
        int node = nb + q * 4 + r;
        bool ok = node < NN;
        int nc = ok ? node : NN - 1;
        float dn = fmaxf(deg[nc], 1.0f);
#pragma unroll
        for (int nt = 0; nt < 4; nt++) {
            int o = nt * 16 + m;
            float av = 0.0f;
            if (ok) {
                av = aggr[(size_t)node * 64 + o];
                aggr[(size_t)node * 64 + o] = 0.0f;   // owner-only self-clear
            }
            float mv = X[nt][r] + av / dn + cb[o];
            ml[w][q * 4 + r][o] = (_Float16)fmaxf(mv, 0.0f);
        }
    }
    __syncthreads();
    h8 ma0 = *(const h8*)&ml[w][m][q * 8];
    h8 ma1 = *(const h8*)&ml[w][m][32 + q * 8];

    f4 GI[12];
#pragma unroll
    for (int nt = 0; nt < 12; nt++) {
        GI[nt] = (f4){0.f, 0.f, 0.f, 0.f};
        GI[nt] = __builtin_amdgcn_mfma_f32_16x16x32_f16(ma0, BW[(8 + nt * 2 + 0) * 64 + lane], GI[nt], 0, 0, 0);
        GI[nt] = __builtin_amdgcn_mfma_f32_16x16x32_f16(ma1, BW[(8 + nt * 2 + 1) * 64 + lane], GI[nt], 0, 0, 0);
    }
#pragma unroll
    for (int og = 0; og < 4; og++) {
        int o = og * 16 + m;
        float bir = bi[o],       bhr = bh[o];
        float biz = bi[64 + o],  bhz = bh[64 + o];
        float bin = bi[128 + o], bhn = bh[128 + o];
#pragma unroll
        for (int r = 0; r < 4; r++) {
            int node = nb + q * 4 + r;
            if (node >= NN) continue;
            float rr = sigf(GI[og][r] + bir + GH[og][r] + bhr);
            float zz = sigf(GI[4 + og][r] + biz + GH[4 + og][r] + bhz);
            float ng = tanhf(GI[8 + og][r] + bin + rr * (GH[8 + og][r] + bhn));
            float hold = s[(size_t)node * 64 + o];
            float hnew = (1.0f - zz) * ng + zz * hold;
            s[(size_t)node * 64 + o] = hnew;
            s16[(size_t)node * 64 + o] = (_Float16)hnew;
        }
    }
}

// Fused Set2Set iteration: LSTM cell + attention pooling, one block(256) per graph.
__global__ void k_s2s(float* __restrict__ q_star, float* __restrict__ hh,
                      float* __restrict__ cc, const float* __restrict__ LiT,
                      const float* __restrict__ LhT, const float* __restrict__ bi,
                      const float* __restrict__ bh, const float* __restrict__ s,
                      const int* __restrict__ gstart, float* __restrict__ e_v) {
    __shared__ float qs[128], hv[64], g[256], qn[64];
    int b = blockIdx.x, t = threadIdx.x;
    if (t < 128) qs[t] = q_star[b * 128 + t];
    else if (t < 192) hv[t - 128] = hh[b * 64 + t - 128];
    __syncthreads();
    float acc = bi[t] + bh[t];
    for (int k = 0; k < 128; k++) acc += qs[k] * LiT[k * 256 + t];
    for (int k = 0; k < 64; k++) acc += hv[k] * LhT[k * 256 + t];
    g[t] = acc;
    __syncthreads();
    if (t < 64) {
        float c_new = sigf(g[64 + t]) * cc[b * 64 + t] + sigf(g[t]) * tanhf(g[128 + t]);
        cc[b * 64 + t] = c_new;
        float hq = sigf(g[192 + t]) * tanhf(c_new);
        hh[b * 64 + t] = hq;
        qn[t] = hq;
        q_star[b * 128 + t] = hq;
    }
    __syncthreads();
    if (t >= 64) return;                 // wave 0 does the pooling
    int o = t;
    int n0 = gstart[b], n1 = gstart[b + 1];
    float q = qn[o];
    float mx = -3.4e38f;
    for (int n = n0; n < n1; n++) {
        float v = s[(size_t)n * 64 + o] * q;
#pragma unroll
        for (int off = 32; off; off >>= 1) v += __shfl_xor(v, off, 64);
        if (o == 0) e_v[n] = v;
        mx = fmaxf(mx, v);
    }
    float asum = 0.0f, rp = 0.0f;
    for (int n = n0; n < n1; n++) {
        float a = __expf(e_v[n] - mx);
        asum += a;
        rp += a * s[(size_t)n * 64 + o];
    }
    q_star[b * 128 + 64 + o] = rp / (asum + 1e-16f);
}

// y[b] = relu(q_star @ lin1 + b1) @ lin2 + b2 ; one wave per graph
__global__ void k_final(const float* __restrict__ q_star, const float* __restrict__ w1,
                        const float* __restrict__ b1, const float* __restrict__ w2,
                        const float* __restrict__ b2, float* __restrict__ y) {
    __shared__ float qs[128];
    int b = blockIdx.x, t = threadIdx.x;  // 64 threads
    qs[t] = q_star[b * 128 + t];
    qs[64 + t] = q_star[b * 128 + 64 + t];
    __syncthreads();
    float acc = b1[t];
    for (int k = 0; k < 128; k++) acc += qs[k] * w1[k * 64 + t];
    float hid = fmaxf(acc, 0.0f) * w2[t];
#pragma unroll
    for (int off = 32; off; off >>= 1) hid += __shfl_down(hid, off, 64);
    if (t == 0) y[b] = hid + b2[0];
}

static inline void zero_f(float* p, size_t nfloats, hipStream_t stream) {
    int n4 = (int)(nfloats / 4);
    k_zero4<<<(n4 + 255) / 256, 256, 0, stream>>>((float4*)p, n4);
}

extern "C" void kernel_launch(void* const* d_in, const int* in_sizes, int n_in,
                              void* d_out, int out_size, void* d_ws, size_t ws_size,
                              hipStream_t stream) {
    const float* x       = (const float*)d_in[0];
    const float* z       = (const float*)d_in[1];
    const float* ea      = (const float*)d_in[2];
    const float* lin0_w  = (const float*)d_in[3];
    const float* lin0_b  = (const float*)d_in[4];
    const float* emlp_w1 = (const float*)d_in[5];
    const float* emlp_b1 = (const float*)d_in[6];
    const float* emlp_w2 = (const float*)d_in[7];
    const float* emlp_b2 = (const float*)d_in[8];
    const float* conv_r  = (const float*)d_in[9];
    const float* conv_b  = (const float*)d_in[10];
    const float* gru_wi  = (const float*)d_in[11];
    const float* gru_wh  = (const float*)d_in[12];
    const float* gru_bi  = (const float*)d_in[13];
    const float* gru_bh  = (const float*)d_in[14];
    const float* lstm_wi = (const float*)d_in[15];
    const float* lstm_wh = (const float*)d_in[16];
    const float* lstm_bi = (const float*)d_in[17];
    const float* lstm_bh = (const float*)d_in[18];
    const float* lin1_w  = (const float*)d_in[19];
    const float* lin1_b  = (const float*)d_in[20];
    const float* lin2_w  = (const float*)d_in[21];
    const float* lin2_b  = (const float*)d_in[22];
    const int* eidx      = (const int*)d_in[23];
    const int* batch     = (const int*)d_in[24];
    const int* srcI = eidx;
    const int* dstI = eidx + NE;
    float* y = (float*)d_out;

    char* w = (char*)d_ws;
    size_t off = 0;
    auto alloc = [&](size_t bytes) -> void* {
        void* p = w + off;
        off += (bytes + 255) & ~(size_t)255;
        return p;
    };
    float* s      = (float*)alloc((size_t)NN * 64 * 4);
    float* aggr   = (float*)alloc((size_t)NN * 64 * 4);
    float* deg    = (float*)alloc((size_t)NN * 4);
    float* e_v    = (float*)alloc((size_t)NN * 4);
    // contiguous zero region: q_star | hh | cc (all 256-multiples)
    float* q_star = (float*)alloc((size_t)NG * 128 * 4);
    float* hh     = (float*)alloc((size_t)NG * 64 * 4);
    float* cc     = (float*)alloc((size_t)NG * 64 * 4);
    float* LiT    = (float*)alloc(256 * 128 * 4);
    float* LhT    = (float*)alloc(256 * 64 * 4);
    int*   gstart = (int*)alloc((size_t)(NG + 1) * 4);
    _Float16* s16 = (_Float16*)alloc((size_t)NN * 64 * 2);
    _Float16* hidT2 = (_Float16*)alloc((size_t)33 * EPAD * 4 * 2);
    _Float16* Bp  = (_Float16*)alloc((size_t)KCH * 4 * 64 * 8 * 2);
    _Float16* Bw  = (_Float16*)alloc((size_t)56 * 64 * 8 * 2);
    (void)ws_size;  // ~64 MB total, well under proven capacity

    // weight prep
    k_transpose<<<(256 * 128 + 255) / 256, 256, 0, stream>>>(LiT, lstm_wi, 256, 128);
    k_transpose<<<(256 * 64 + 255) / 256, 256, 0, stream>>>(LhT, lstm_wh, 256, 64);
    k_prep_W<<<14, 256, 0, stream>>>(conv_r, gru_wi, gru_wh, Bw);

    // node embedding, degree, graph ranges, edge-MLP layer 1 (-> hidT2 f16), B prep
    k_lin0<<<NN * 64 / 256, 256, 0, stream>>>(x, z, lin0_w, lin0_b, s);
    k_s16<<<NN * 16 / 256, 256, 0, stream>>>(s, s16);
    zero_f(deg, NN, stream);
    k_deg<<<(NE + 255) / 256, 256, 0, stream>>>(dstI, deg);
    k_gstart<<<(NN + 256) / 256, 256, 0, stream>>>(batch, gstart);
    k_emlp_t<<<EPAD / 64, 256, 0, stream>>>(ea, emlp_w1, emlp_b1, hidT2);
    k_prep_B<<<KCH * 4 * 64 / 256, 256, 0, stream>>>(emlp_w2, emlp_b2, Bp);

    // 5 message-passing + GRU steps (aggr zeroed once; k_combine2 self-clears it)
    zero_f(aggr, (size_t)NN * 64, stream);
    for (int step = 0; step < 5; step++) {
        k_fused<<<EPAD / 128, 128, 0, stream>>>(s16, hidT2, Bp, srcI, dstI, aggr);
        k_combine2<<<(NN + 63) / 64, 256, 0, stream>>>(s, s16, aggr, deg, Bw,
                                                       conv_b, gru_bi, gru_bh);
    }

    // Set2Set: 5 fused LSTM+pool iterations
    zero_f(q_star, (size_t)NG * 128 + NG * 64 + NG * 64, stream);
    for (int it = 0; it < 5; it++) {
        k_s2s<<<NG, 256, 0, stream>>>(q_star, hh, cc, LiT, LhT, lstm_bi, lstm_bh,
                                      s, gstart, e_v);
    }
    k_final<<<NG, 64, 0, stream>>>(q_star, lin1_w, lin1_b, lin2_w, lin2_b, y);
}